// Round 3
// baseline (1619.888 us; speedup 1.0000x reference)
//
#include <hip/hip_runtime.h>
#include <cmath>

// CfC-NCP RNN, phase-decomposed + chunk-pipelined.
// R8: r12 lag-2 -> lag-1 (saves one ~74 us launch slot).
//  - x1 folded into r12 l1: each l1 wave runs 9 k-tiles (5 input from nh0 +
//    4 recurrent from LDS) with bias acc-init. nh0 A-tiles are loaded
//    global->register with a 2-step prefetch lead (Aa/Ab sets, ~2 us, covers
//    L3/cross-XCD latency). No LDS staging, no stager waves (R6's failure).
//  - XU1 + x1 bulk pass deleted. r12(c-1) runs in launch c.
//  - __launch_bounds__(640, 1) relaxes the VGPR cap so l1's resident arrays
//    (BfI 60 + BfR 48 + Aa/Ab 40 VGPRs) are NOT sunk into the loop (R6's
//    VGPR_Count=84 showed the compiler rematerializing weight loads per step).
//    Wave 7 (l2) reuses BfR storage for its weights.
//  - exp2 pre-scale: weights & biases carry log2(e) so cfc_h uses v_exp_f32
//    directly (3 fewer v_mul per output element on the critical epilogue).
// Chain: pack; R(-1)[x0(0)]; R(0..7)[r0(c)|r12(c-1)|x0(c+1)]; R(8)[r12(7)].
// 10 slots. Carried: packed weights, merged -(ts*wa+wb), -2 pre-scale, depth-4
// r0 xu prefetch, raw lgkmcnt-only barriers, single-rcp epilogue.

typedef _Float16 f16;
typedef f16 h4 __attribute__((ext_vector_type(4)));
typedef f16 h8 __attribute__((ext_vector_type(8)));
typedef float f4 __attribute__((ext_vector_type(4)));

#define MFMA(a, b, c) __builtin_amdgcn_mfma_f32_16x16x32_f16(a, b, c, 0, 0, 0)
// LDS-only barrier: waves drain their own LDS ops (lgkmcnt) then sync; global ops
// (prefetch loads, NH0/y stores) intentionally left in flight.
#define RAW_BAR() asm volatile("s_waitcnt lgkmcnt(0)\n\ts_barrier" ::: "memory")

constexpr int IN_DIM = 128, Ni = 149, Nc = 99, Nm = 8;
constexpr int CAT0 = 277, CAT1 = 248, CAT2 = 107;
constexpr int Bsz = 256, Tsz = 512;
constexpr int TC = 64, NCH = 8, NBT = 16;
constexpr int NT0 = 30;                  // layer-0 fragment tile-columns (3 mats x 10)
constexpr int S0 = 168, S2 = 136;        // LDS row strides (halves), bank-conflict pad
constexpr int NXWG0 = 128;               // x0 workgroups per R launch
constexpr size_t XU0C = (size_t)TC * NBT * NT0 * 256;  // 7,864,320 halves / buffer
constexpr size_t NH0C = (size_t)TC * NBT * 2560;       // 2,621,440 halves / buffer
constexpr size_t H0S_HALVES = (size_t)NBT * 16 * S0;
constexpr size_t H12S_HALVES = (size_t)NBT * 2 * 16 * S2;
constexpr size_t YOFF = (size_t)Bsz * Tsz * 8;  // h_out offset in d_out
constexpr float L2E = 1.4426950408889634f;      // log2(e), folded into weights

// packed-fragment segment offsets (h8 units); mat2 = merged -(ts*wa+wb)
constexpr int OFF_X0 = 0;          // [mat3][nt10][kt4][lane64]
constexpr int OFF_R0 = 7680;       // [g10][mat3][kt5][lane64]
constexpr int OFF_X1 = 17280;      // [mat3][nt7][kt5][lane64]
constexpr int OFF_R12A = 24000;    // [w7][mat3][kt4][lane64]
constexpr int OFF_R12B = 29376;    // [mat3][kt4][lane64]
constexpr int NFRAG = 30144;

__device__ inline float rcpf_(float x) { return __builtin_amdgcn_rcpf(x); }
__device__ __forceinline__ float exp2p_(float x) {
#if __has_builtin(__builtin_amdgcn_exp2f)
  return __builtin_amdgcn_exp2f(x);
#else
  return exp2f(x);
#endif
}
// h = ff1 + (ff2-ff1)*ti with ff=(1-e)/(1+e), ti=1/(1+c).
// a0=-2u1*L2E, a1=-2u2*L2E, a2=-z*L2E (scales pre-folded into weights/biases).
__device__ __forceinline__ float cfc_h(float a0, float a1, float a2) {
  float e0 = exp2p_(a0), e1 = exp2p_(a1), e2 = exp2p_(a2);
  float pa = 1.f + e0, ma = 1.f - e0;
  float pb = 1.f + e1, mb = 1.f - e1;
  float pc = 1.f + e2;
  float num = fmaf(ma * pb, e2, mb * pa);
  return num * rcpf_(pa * pb * pc);
}
__device__ __forceinline__ float tanhp_(float x) {  // tanh(x)
  float e = exp2p_(-2.f * L2E * x);
  return (1.f - e) * rcpf_(1.f + e);
}

// ---------------- pack: build all h8 weight fragments once per call ------------------
__global__ __launch_bounds__(256) void pack_kernel(
    const float* __restrict__ w1_0, const float* __restrict__ w2_0,
    const float* __restrict__ wa_0, const float* __restrict__ wb_0,
    const int* __restrict__ m0,
    const float* __restrict__ w1_1, const float* __restrict__ w2_1,
    const float* __restrict__ wa_1, const float* __restrict__ wb_1,
    const int* __restrict__ m1,
    const float* __restrict__ w1_2, const float* __restrict__ w2_2,
    const float* __restrict__ wa_2, const float* __restrict__ wb_2,
    const int* __restrict__ m2, const float* __restrict__ dtp,
    f16* __restrict__ PK) {
  int idx = blockIdx.x * 256 + threadIdx.x;
  if (idx >= NFRAG) return;
  int lane = idx & 63, col = lane & 15, q = lane >> 4;
  float ts = dtp[0];
  const float* Wa = nullptr;
  const float* Wb = nullptr;
  const int* M = nullptr;
  int ld, n, nmax, k0, kmax;
  int mat;
  if (idx < OFF_R0) {  // x0 input-part
    int p = idx >> 6;
    mat = p / 40; int nt = (p >> 2) % 10, kt = p & 3;
    ld = CAT0; n = nt * 16 + col; nmax = Ni; k0 = kt * 32 + q * 8; kmax = IN_DIM;
    if (mat == 0) { Wa = w1_0; M = m0; }
    else if (mat == 1) { Wa = w2_0; M = m0; }
    else { Wa = wa_0; Wb = wb_0; }
  } else if (idx < OFF_X1) {  // r0 recurrent-part
    int p = (idx - OFF_R0) >> 6;
    int g = p / 15; mat = (p / 5) % 3; int kt = p % 5;
    ld = CAT0; n = g * 16 + col; nmax = Ni; k0 = IN_DIM + kt * 32 + q * 8; kmax = CAT0;
    if (mat == 0) Wa = w1_0;
    else if (mat == 1) Wa = w2_0;
    else { Wa = wa_0; Wb = wb_0; }
  } else if (idx < OFF_R12A) {  // x1 input-part (consumed per-step by r12 l1)
    int p = (idx - OFF_X1) >> 6;
    mat = p / 35; int nt = (p / 5) % 7, kt = p % 5;
    ld = CAT1; n = nt * 16 + col; nmax = Nc; k0 = kt * 32 + q * 8; kmax = Ni;
    if (mat == 0) { Wa = w1_1; M = m1; }
    else if (mat == 1) { Wa = w2_1; M = m1; }
    else { Wa = wa_1; Wb = wb_1; }
  } else if (idx < OFF_R12B) {  // r12 layer1 recurrent-part
    int p = (idx - OFF_R12A) >> 6;
    int wv = p / 12; mat = (p / 4) % 3; int kt = p & 3;
    ld = CAT1; n = wv * 16 + col; nmax = Nc; k0 = Ni + kt * 32 + q * 8; kmax = CAT1;
    if (mat == 0) Wa = w1_1;
    else if (mat == 1) Wa = w2_1;
    else { Wa = wa_1; Wb = wb_1; }
  } else {  // r12 layer2 (full cat)
    int p = (idx - OFF_R12B) >> 6;
    mat = p / 4; int kt = p & 3;
    ld = CAT2; n = col; nmax = Nm; k0 = kt * 32 + q * 8; kmax = CAT2;
    if (mat == 0) { Wa = w1_2; M = m2; }
    else if (mat == 1) { Wa = w2_2; M = m2; }
    else { Wa = wa_2; Wb = wb_2; }
  }
  h8 r;
#pragma unroll
  for (int j = 0; j < 8; j++) {
    int k = k0 + j;
    float v = 0.f;
    if (n < nmax && k < kmax) {
      if (mat < 2) {
        v = Wa[(size_t)n * ld + k];
        if (M) v *= (float)M[(size_t)n * ld + k];
        v *= -2.f * L2E;                 // ff pre-scale: acc = -2u*log2(e)
      } else {
        v = -L2E * (ts * Wa[(size_t)n * ld + k] + Wb[(size_t)n * ld + k]);
      }
    }
    r[j] = (f16)v;
  }
  ((h8*)PK)[idx] = r;
}

// ------- r0 one step: consume xu (t), reload xu for t+4 (depth-4 pipeline) -----------
__device__ __forceinline__ void r0_step(
    const f16* br, f16* bw, const f16* __restrict__ XU0, f16* __restrict__ NH0,
    float* __restrict__ out, const h8 (&Bf)[3][5], h4 (&xu)[3],
    int t, int tload, int bt, int g, int lane, int col, int q, int n, bool last) {
  h8 A[5];
#pragma unroll
  for (int kt = 0; kt < 5; kt++)
    A[kt] = *(const h8*)(br + col * S0 + kt * 32 + q * 8);
  f4 acc0 = {(float)xu[0][0], (float)xu[0][1], (float)xu[0][2], (float)xu[0][3]};
  f4 acc1 = {(float)xu[1][0], (float)xu[1][1], (float)xu[1][2], (float)xu[1][3]};
  f4 acc2 = {(float)xu[2][0], (float)xu[2][1], (float)xu[2][2], (float)xu[2][3]};
  size_t mtl = (size_t)tload * NBT + bt;
#pragma unroll
  for (int mat = 0; mat < 3; mat++)
    xu[mat] = *(const h4*)(XU0 + (mtl * NT0 + mat * 10 + g) * 256 + lane * 4);
#pragma unroll
  for (int kt = 0; kt < 5; kt++) {
    acc0 = MFMA(A[kt], Bf[0][kt], acc0);
    acc1 = MFMA(A[kt], Bf[1][kt], acc1);
    acc2 = MFMA(A[kt], Bf[2][kt], acc2);
  }
  int mt = t * NBT + bt;
  f16* nh = NH0 + (size_t)mt * 2560;
#pragma unroll
  for (int r = 0; r < 4; r++) {
    int m = q * 4 + r;
    float h = cfc_h(acc0[r], acc1[r], acc2[r]);
    f16 h16 = (f16)h;
    bw[m * S0 + n] = h16;
    nh[m * 160 + n] = h16;   // cols >= Ni are exact zeros (zero weights+bias)
    if (last && n < Ni) out[YOFF + (size_t)(bt * 16 + m) * 256 + n] = h;
  }
}

// ------- r12 layer1 one step: 5 input kt (A regs, nh0) + 4 recurrent kt (LDS);
// ------- reloads A for t+2 after the MFMAs (2-step global prefetch lead) ------------
__device__ __forceinline__ void r12l1_step(
    const f16* br, f16* bw, const f16* __restrict__ NH0r, float* __restrict__ out,
    const h8 (&BfI)[3][5], const h8 (&BfR)[3][4], h8 (&A)[5],
    float bn0, float bn1, float bn2,
    int tload, int bt, int col, int q, int n, bool last) {
  h8 Ar[4];
#pragma unroll
  for (int kt = 0; kt < 4; kt++)
    Ar[kt] = *(const h8*)(br + col * S2 + kt * 32 + q * 8);
  f4 acc0 = {bn0, bn0, bn0, bn0};
  f4 acc1 = {bn1, bn1, bn1, bn1};
  f4 acc2 = {bn2, bn2, bn2, bn2};
#pragma unroll
  for (int kt = 0; kt < 5; kt++) {
    acc0 = MFMA(A[kt], BfI[0][kt], acc0);
    acc1 = MFMA(A[kt], BfI[1][kt], acc1);
    acc2 = MFMA(A[kt], BfI[2][kt], acc2);
  }
#pragma unroll
  for (int kt = 0; kt < 4; kt++) {
    acc0 = MFMA(Ar[kt], BfR[0][kt], acc0);
    acc1 = MFMA(Ar[kt], BfR[1][kt], acc1);
    acc2 = MFMA(Ar[kt], BfR[2][kt], acc2);
  }
  const f16* Ab = NH0r + ((size_t)tload * NBT + bt) * 2560;
#pragma unroll
  for (int kt = 0; kt < 5; kt++)
    A[kt] = *(const h8*)(Ab + col * 160 + kt * 32 + q * 8);
#pragma unroll
  for (int r = 0; r < 4; r++) {
    int m = q * 4 + r;
    float h = cfc_h(acc0[r], acc1[r], acc2[r]);
    if (n < Nc) {
      bw[m * S2 + n] = (f16)h;
      if (last) out[YOFF + (size_t)(bt * 16 + m) * 256 + Ni + n] = h;
    }
  }
}

// ------- r12 layer2 one step: reads rb (nh1(t)|h2(t-1)), writes h2(t) into wb --------
__device__ __forceinline__ void r12l2_step(
    const f16* rb, f16* wb, float* __restrict__ out, const h8 (&Bf)[3][4],
    float bn0, float bn1, float bn2, int tg, int bt, int col, int q, bool last) {
  h8 A[4];
#pragma unroll
  for (int kt = 0; kt < 4; kt++)
    A[kt] = *(const h8*)(rb + col * S2 + kt * 32 + q * 8);
  f4 acc0 = {bn0, bn0, bn0, bn0};
  f4 acc1 = {bn1, bn1, bn1, bn1};
  f4 acc2 = {bn2, bn2, bn2, bn2};
#pragma unroll
  for (int kt = 0; kt < 4; kt++) {
    acc0 = MFMA(A[kt], Bf[0][kt], acc0);
    acc1 = MFMA(A[kt], Bf[1][kt], acc1);
    acc2 = MFMA(A[kt], Bf[2][kt], acc2);
  }
#pragma unroll
  for (int r = 0; r < 4; r++) {
    int m = q * 4 + r;
    float h = cfc_h(acc0[r], acc1[r], acc2[r]);
    if (col < Nm) {
      out[((size_t)(bt * 16 + m) * Tsz + tg) * 8 + col] = tanhp_(h);
      wb[m * S2 + Nc + col] = (f16)h;
      if (last) out[YOFF + (size_t)(bt * 16 + m) * 256 + Ni + Nc + col] = h;
    }
  }
}

// ---- R: [r0(c) 0-15 | r12(c-1) 16-31 | x0(c+1) 32-159] ------------------------------
__global__ __launch_bounds__(640, 1) void R_kernel(
    const h8* __restrict__ pk,
    const float* __restrict__ b1_0, const float* __restrict__ b2_0,
    const float* __restrict__ ba_0, const float* __restrict__ bb_0,
    const float* __restrict__ b1_1, const float* __restrict__ b2_1,
    const float* __restrict__ ba_1, const float* __restrict__ bb_1,
    const float* __restrict__ c1, const float* __restrict__ c2,
    const float* __restrict__ ca, const float* __restrict__ cb,
    const float* __restrict__ dtp, const float* __restrict__ x,
    f16* __restrict__ XU0, f16* __restrict__ NH0,
    f16* __restrict__ H0S, f16* __restrict__ H12S,
    float* __restrict__ out, int c) {
  __shared__ __align__(16) char smem[10752];  // union: r0 10752 / r12 8704 / x0 4352
  int tid = threadIdx.x;
  int g = tid >> 6, lane = tid & 63, col = lane & 15, q = lane >> 4;
  int wg = blockIdx.x;
  float ts = dtp[0];

  if (wg < NBT) {  // ================= r0, chunk c =================
    if (c < 0 || c >= NCH) return;
    const f16* XU0r = XU0 + (size_t)(c & 1) * XU0C;
    f16* NH0w = NH0 + (size_t)(c & 1) * NH0C;
    f16(*buf)[16 * S0] = (f16(*)[16 * S0])smem;
    int bt = wg;
    int n = g * 16 + col;                      // output neuron (0..159, valid <149)
    h8 Bf[3][5];                               // recurrent weights, resident
#pragma unroll
    for (int mat = 0; mat < 3; mat++)
#pragma unroll
      for (int kt = 0; kt < 5; kt++)
        Bf[mat][kt] = pk[OFF_R0 + ((g * 3 + mat) * 5 + kt) * 64 + lane];

    for (int idx = tid; idx < 16 * S0; idx += 640) {
      buf[0][idx] = (c == 0) ? (f16)0.f : H0S[(size_t)bt * 16 * S0 + idx];
      buf[1][idx] = (f16)0.f;
    }
    __syncthreads();

    h4 xu0[3], xu1[3], xu2[3], xu3[3];         // depth-4 prefetch (2-step lead)
#pragma unroll
    for (int mat = 0; mat < 3; mat++) {
      xu0[mat] = *(const h4*)(XU0r + ((size_t)(0 * NBT + bt) * NT0 + mat * 10 + g) * 256 + lane * 4);
      xu1[mat] = *(const h4*)(XU0r + ((size_t)(1 * NBT + bt) * NT0 + mat * 10 + g) * 256 + lane * 4);
      xu2[mat] = *(const h4*)(XU0r + ((size_t)(2 * NBT + bt) * NT0 + mat * 10 + g) * 256 + lane * 4);
      xu3[mat] = *(const h4*)(XU0r + ((size_t)(3 * NBT + bt) * NT0 + mat * 10 + g) * 256 + lane * 4);
    }

    for (int t = 0; t < TC; t += 4) {
      r0_step(buf[0], buf[1], XU0r, NH0w, out, Bf, xu0, t, (t + 4 < TC) ? t + 4 : t,
              bt, g, lane, col, q, n, false);
      RAW_BAR();
      r0_step(buf[1], buf[0], XU0r, NH0w, out, Bf, xu1, t + 1,
              (t + 5 < TC) ? t + 5 : t + 1, bt, g, lane, col, q, n, false);
      RAW_BAR();
      r0_step(buf[0], buf[1], XU0r, NH0w, out, Bf, xu2, t + 2,
              (t + 6 < TC) ? t + 6 : t + 2, bt, g, lane, col, q, n, false);
      RAW_BAR();
      bool lastD = (c == NCH - 1) && (t + 3 == TC - 1);
      r0_step(buf[1], buf[0], XU0r, NH0w, out, Bf, xu3, t + 3,
              (t + 7 < TC) ? t + 7 : t + 3, bt, g, lane, col, q, n, lastD);
      RAW_BAR();
    }
    for (int idx = tid; idx < 16 * S0; idx += 640)
      H0S[(size_t)bt * 16 * S0 + idx] = buf[0][idx];

  } else if (wg < 2 * NBT) {  // ================= r12, chunk cc = c-1 =================
    int cc = c - 1;
    if (cc < 0 || cc >= NCH) return;
    const f16* NH0r = NH0 + (size_t)(cc & 1) * NH0C;
    f16(*buf)[16 * S2] = (f16(*)[16 * S2])smem;
    int bt = wg - NBT;
    int w = g;                                 // 0-6 l1, 7 l2, 8-9 barrier-only
    int n = w * 16 + col;
    h8 BfI[3][5];                              // l1 input-part weights (nh0 k-range)
    h8 BfR[3][4];                              // l1 recurrent weights; l2 reuses
    float bn0 = 0.f, bn1 = 0.f, bn2 = 0.f;
    if (w < 7) {
#pragma unroll
      for (int mat = 0; mat < 3; mat++) {
#pragma unroll
        for (int kt = 0; kt < 5; kt++)
          BfI[mat][kt] = pk[OFF_X1 + (mat * 35 + w * 5 + kt) * 64 + lane];
#pragma unroll
        for (int kt = 0; kt < 4; kt++)
          BfR[mat][kt] = pk[OFF_R12A + ((w * 3 + mat) * 4 + kt) * 64 + lane];
      }
      bn0 = (n < Nc) ? -2.f * L2E * b1_1[n] : 0.f;
      bn1 = (n < Nc) ? -2.f * L2E * b2_1[n] : 0.f;
      bn2 = (n < Nc) ? -L2E * (ts * ba_1[n] + bb_1[n]) : 0.f;
    } else if (w == 7) {
#pragma unroll
      for (int mat = 0; mat < 3; mat++)
#pragma unroll
        for (int kt = 0; kt < 4; kt++)
          BfR[mat][kt] = pk[OFF_R12B + (mat * 4 + kt) * 64 + lane];
      bn0 = (col < Nm) ? -2.f * L2E * c1[col] : 0.f;
      bn1 = (col < Nm) ? -2.f * L2E * c2[col] : 0.f;
      bn2 = (col < Nm) ? -L2E * (ts * ca[col] + cb[col]) : 0.f;
    }
    h8 Aa[5], Ab[5];                           // nh0 A-tiles, 2-step prefetch
    if (w < 7) {
      const f16* A0 = NH0r + (size_t)(0 * NBT + bt) * 2560;
      const f16* A1 = NH0r + (size_t)(1 * NBT + bt) * 2560;
#pragma unroll
      for (int kt = 0; kt < 5; kt++) {
        Aa[kt] = *(const h8*)(A0 + col * 160 + kt * 32 + q * 8);
        Ab[kt] = *(const h8*)(A1 + col * 160 + kt * 32 + q * 8);
      }
    }
    for (int idx = tid; idx < 2 * 16 * S2; idx += 640)
      ((f16*)buf)[idx] = (cc == 0) ? (f16)0.f : H12S[(size_t)bt * 2 * 16 * S2 + idx];
    __syncthreads();

    for (int t = 0; t < TC; t += 2) {
      if (w < 7)
        r12l1_step(buf[0], buf[1], NH0r, out, BfI, BfR, Aa, bn0, bn1, bn2,
                   (t + 2 < TC) ? t + 2 : t, bt, col, q, n, false);
      RAW_BAR();
      if (w == 7)
        r12l2_step(buf[1], buf[0], out, BfR, bn0, bn1, bn2, cc * TC + t, bt, col, q,
                   false);
      if (w < 7) {
        bool lastB = (cc == NCH - 1) && (t + 1 == TC - 1);
        r12l1_step(buf[1], buf[0], NH0r, out, BfI, BfR, Ab, bn0, bn1, bn2,
                   (t + 3 < TC) ? t + 3 : t + 1, bt, col, q, n, lastB);
      }
      RAW_BAR();
      if (w == 7)
        r12l2_step(buf[0], buf[1], out, BfR, bn0, bn1, bn2, cc * TC + t + 1, bt, col, q,
                   (cc == NCH - 1) && (t + 1 == TC - 1));
    }
    __syncthreads();
    for (int idx = tid; idx < 2 * 16 * S2; idx += 640)
      H12S[(size_t)bt * 2 * 16 * S2 + idx] = ((f16*)buf)[idx];

  } else {  // ================= x0 for chunk c+1 (no recurrence dep) =================
    int cn = c + 1;
    if (cn >= NCH) return;
    f16* XU0w = XU0 + (size_t)(cn & 1) * XU0C;
    f16* stg = (f16*)smem;                     // 16 x 136
    int bx = wg - 2 * NBT;                     // 0..NXWG0-1
    int w = g;                                 // wave -> output tile g=w, all 3 mats
    int n = w * 16 + col;
    h8 Bx[3][4];
    float bias[3];
#pragma unroll
    for (int mat = 0; mat < 3; mat++)
#pragma unroll
      for (int kt = 0; kt < 4; kt++)
        Bx[mat][kt] = pk[OFF_X0 + ((mat * 10 + w) * 4 + kt) * 64 + lane];
    bias[0] = (n < Ni) ? -2.f * L2E * b1_0[n] : 0.f;
    bias[1] = (n < Ni) ? -2.f * L2E * b2_0[n] : 0.f;
    bias[2] = (n < Ni) ? -L2E * (ts * ba_0[n] + bb_0[n]) : 0.f;
    for (int i = 0; i < (TC * NBT) / NXWG0; i++) {   // 8 mt tiles per WG
      int mt = bx * ((TC * NBT) / NXWG0) + i;
      int tl = mt >> 4, bt = mt & 15;
      int tg = cn * TC + tl;
      if (tid < 256) {
        int sr = tid >> 4, sc = (tid & 15) * 8;
        const float* xp = x + ((size_t)(bt * 16 + sr) * Tsz + tg) * IN_DIM + sc;
        h8 hv;
#pragma unroll
        for (int j = 0; j < 8; j++) hv[j] = (f16)xp[j];
        *(h8*)(stg + sr * 136 + sc) = hv;
      }
      __syncthreads();
      h8 A[4];
#pragma unroll
      for (int kt = 0; kt < 4; kt++)
        A[kt] = *(const h8*)(stg + col * 136 + kt * 32 + q * 8);
#pragma unroll
      for (int mat = 0; mat < 3; mat++) {
        float b = bias[mat];
        f4 acc = {b, b, b, b};
#pragma unroll
        for (int kt = 0; kt < 4; kt++) acc = MFMA(A[kt], Bx[mat][kt], acc);
        h4 o;
#pragma unroll
        for (int rr = 0; rr < 4; rr++) o[rr] = (f16)acc[rr];
        *(h4*)(XU0w + ((size_t)mt * NT0 + mat * 10 + w) * 256 + lane * 4) = o;
      }
      __syncthreads();
    }
  }
}

extern "C" void kernel_launch(void* const* d_in, const int* in_sizes, int n_in,
                              void* d_out, int out_size, void* d_ws, size_t ws_size,
                              hipStream_t stream) {
  const float* w1_0 = (const float*)d_in[0];
  const float* w2_0 = (const float*)d_in[1];
  const float* wa_0 = (const float*)d_in[2];
  const float* wb_0 = (const float*)d_in[3];
  const float* b1_0 = (const float*)d_in[4];
  const float* b2_0 = (const float*)d_in[5];
  const float* ba_0 = (const float*)d_in[6];
  const float* bb_0 = (const float*)d_in[7];
  const int* m0 = (const int*)d_in[8];
  const float* w1_1 = (const float*)d_in[9];
  const float* w2_1 = (const float*)d_in[10];
  const float* wa_1 = (const float*)d_in[11];
  const float* wb_1 = (const float*)d_in[12];
  const float* b1_1 = (const float*)d_in[13];
  const float* b2_1 = (const float*)d_in[14];
  const float* ba_1 = (const float*)d_in[15];
  const float* bb_1 = (const float*)d_in[16];
  const int* m1 = (const int*)d_in[17];
  const float* w1_2 = (const float*)d_in[18];
  const float* w2_2 = (const float*)d_in[19];
  const float* wa_2 = (const float*)d_in[20];
  const float* wb_2 = (const float*)d_in[21];
  const float* c1 = (const float*)d_in[22];
  const float* c2 = (const float*)d_in[23];
  const float* ca = (const float*)d_in[24];
  const float* cb = (const float*)d_in[25];
  const int* m2 = (const int*)d_in[26];
  const float* x = (const float*)d_in[27];
  const float* dt = (const float*)d_in[28];
  float* out = (float*)d_out;

  f16* XU0 = (f16*)d_ws;                 // 2 x XU0C
  f16* NH0 = XU0 + 2 * XU0C;             // 2 x NH0C
  f16* H0S = NH0 + 2 * NH0C;
  f16* H12S = H0S + H0S_HALVES;
  f16* PK = H12S + H12S_HALVES;
  const h8* pk = (const h8*)PK;

  pack_kernel<<<(NFRAG + 255) / 256, 256, 0, stream>>>(
      w1_0, w2_0, wa_0, wb_0, m0, w1_1, w2_1, wa_1, wb_1, m1,
      w1_2, w2_2, wa_2, wb_2, m2, dt, PK);

  for (int c = -1; c <= NCH; c++)
    R_kernel<<<2 * NBT + NXWG0, 640, 0, stream>>>(
        pk, b1_0, b2_0, ba_0, bb_0, b1_1, b2_1, ba_1, bb_1,
        c1, c2, ca, cb, dt, x, XU0, NH0, H0S, H12S, out, c);
}

// Round 4
// 1004.389 us; speedup vs baseline: 1.6128x; 1.6128x over previous
//
#include <hip/hip_runtime.h>
#include <hip/hip_cooperative_groups.h>
#include <cmath>

// CfC-NCP RNN, phase-decomposed + chunk-pipelined.
// R9: single persistent cooperative kernel. R7's proven structure (772 us) with
// the 11 launches + pack fused into one kernel; grid.sync() between phases.
//  - Phase loop ph=-1..NCH+1: [ r0(ph) | r12(ph-2) | x1(ph-1) | x0(ph+1) ] on
//    disjoint WG ranges (16 | 16 | 64 | 128 = 224 WGs, 1/CU, co-resident).
//  - Kills the measured ~8 us/launch gap, per-launch weight reloads, and the
//    H0S/H12S recurrent-state roundtrips (state stays LDS-resident).
//  - pack runs as phase -2 inside the same kernel (one thread per fragment).
//  - grid.sync() (cooperative groups) provides the cross-XCD L2 writeback/
//    invalidate the kernel boundary used to provide.
// R8 lesson: l1 cannot hold 108 resident weight VGPRs (allocator remats loads
// into the loop; VGPR_Count=84 proved it) -> r12 stays lag-2 with bulk x1.
// Carried from R1-R8: packed weights, merged -(ts*wa+wb), -2*log2e pre-scale,
// depth-4 r0 xu prefetch, depth-2 r12 xu prefetch, raw lgkmcnt-only barriers,
// single-rcp epilogue, exp2-based cfc_h.

namespace cg = cooperative_groups;

typedef _Float16 f16;
typedef f16 h4 __attribute__((ext_vector_type(4)));
typedef f16 h8 __attribute__((ext_vector_type(8)));
typedef float f4 __attribute__((ext_vector_type(4)));

#define MFMA(a, b, c) __builtin_amdgcn_mfma_f32_16x16x32_f16(a, b, c, 0, 0, 0)
// LDS-only barrier: waves drain their own LDS ops (lgkmcnt) then sync; global ops
// (prefetch loads, NH0/y stores) intentionally left in flight.
#define RAW_BAR() asm volatile("s_waitcnt lgkmcnt(0)\n\ts_barrier" ::: "memory")

constexpr int IN_DIM = 128, Ni = 149, Nc = 99, Nm = 8;
constexpr int CAT0 = 277, CAT1 = 248, CAT2 = 107;
constexpr int Bsz = 256, Tsz = 512;
constexpr int TC = 64, NCH = 8, NBT = 16;
constexpr int NT0 = 30, NT1 = 21;        // fragment tile-columns (3 mats x n-tiles)
constexpr int S0 = 168, S2 = 136;        // LDS row strides (halves), bank-conflict pad
constexpr int NXWG1 = 64;                // x1 workgroups
constexpr int NXWG0 = 128;               // x0 workgroups
constexpr int NWG = 2 * NBT + NXWG1 + NXWG0;  // 224
constexpr size_t XU0C = (size_t)TC * NBT * NT0 * 256;  // 7,864,320 halves / buffer
constexpr size_t NH0C = (size_t)TC * NBT * 2560;       // 2,621,440 halves / buffer
constexpr size_t XU1C = (size_t)TC * NBT * NT1 * 256;  // 5,505,024 halves / buffer
constexpr size_t YOFF = (size_t)Bsz * Tsz * 8;  // h_out offset in d_out
constexpr float L2E = 1.4426950408889634f;      // log2(e), folded into weights

// packed-fragment segment offsets (h8 units); mat2 = merged -(ts*wa+wb)
constexpr int OFF_X0 = 0;          // [mat3][nt10][kt4][lane64]
constexpr int OFF_R0 = 7680;       // [g10][mat3][kt5][lane64]
constexpr int OFF_X1 = 17280;      // [mat3][nt7][kt5][lane64]
constexpr int OFF_R12A = 24000;    // [w7][mat3][kt4][lane64]
constexpr int OFF_R12B = 29376;    // [mat3][kt4][lane64]
constexpr int NFRAG = 30144;

__device__ inline float rcpf_(float x) { return __builtin_amdgcn_rcpf(x); }
__device__ __forceinline__ float exp2p_(float x) {
#if __has_builtin(__builtin_amdgcn_exp2f)
  return __builtin_amdgcn_exp2f(x);
#else
  return exp2f(x);
#endif
}
// h = ff1 + (ff2-ff1)*ti with ff=(1-e)/(1+e), ti=1/(1+c).
// a0=-2u1*L2E, a1=-2u2*L2E, a2=-z*L2E (scales pre-folded into weights/biases).
__device__ __forceinline__ float cfc_h(float a0, float a1, float a2) {
  float e0 = exp2p_(a0), e1 = exp2p_(a1), e2 = exp2p_(a2);
  float pa = 1.f + e0, ma = 1.f - e0;
  float pb = 1.f + e1, mb = 1.f - e1;
  float pc = 1.f + e2;
  float num = fmaf(ma * pb, e2, mb * pa);
  return num * rcpf_(pa * pb * pc);
}
__device__ __forceinline__ float tanhp_(float x) {  // tanh(x)
  float e = exp2p_(-2.f * L2E * x);
  return (1.f - e) * rcpf_(1.f + e);
}

// ---------------- pack one h8 weight fragment (phase -2, one thread each) -----------
__device__ __forceinline__ void pack_one(
    int idx,
    const float* __restrict__ w1_0, const float* __restrict__ w2_0,
    const float* __restrict__ wa_0, const float* __restrict__ wb_0,
    const int* __restrict__ m0,
    const float* __restrict__ w1_1, const float* __restrict__ w2_1,
    const float* __restrict__ wa_1, const float* __restrict__ wb_1,
    const int* __restrict__ m1,
    const float* __restrict__ w1_2, const float* __restrict__ w2_2,
    const float* __restrict__ wa_2, const float* __restrict__ wb_2,
    const int* __restrict__ m2, float ts, f16* __restrict__ PK) {
  int lane = idx & 63, col = lane & 15, q = lane >> 4;
  const float* Wa = nullptr;
  const float* Wb = nullptr;
  const int* M = nullptr;
  int ld, n, nmax, k0, kmax;
  int mat;
  if (idx < OFF_R0) {  // x0 input-part
    int p = idx >> 6;
    mat = p / 40; int nt = (p >> 2) % 10, kt = p & 3;
    ld = CAT0; n = nt * 16 + col; nmax = Ni; k0 = kt * 32 + q * 8; kmax = IN_DIM;
    if (mat == 0) { Wa = w1_0; M = m0; }
    else if (mat == 1) { Wa = w2_0; M = m0; }
    else { Wa = wa_0; Wb = wb_0; }
  } else if (idx < OFF_X1) {  // r0 recurrent-part
    int p = (idx - OFF_R0) >> 6;
    int g = p / 15; mat = (p / 5) % 3; int kt = p % 5;
    ld = CAT0; n = g * 16 + col; nmax = Ni; k0 = IN_DIM + kt * 32 + q * 8; kmax = CAT0;
    if (mat == 0) Wa = w1_0;
    else if (mat == 1) Wa = w2_0;
    else { Wa = wa_0; Wb = wb_0; }
  } else if (idx < OFF_R12A) {  // x1 input-part
    int p = (idx - OFF_X1) >> 6;
    mat = p / 35; int nt = (p / 5) % 7, kt = p % 5;
    ld = CAT1; n = nt * 16 + col; nmax = Nc; k0 = kt * 32 + q * 8; kmax = Ni;
    if (mat == 0) { Wa = w1_1; M = m1; }
    else if (mat == 1) { Wa = w2_1; M = m1; }
    else { Wa = wa_1; Wb = wb_1; }
  } else if (idx < OFF_R12B) {  // r12 layer1 recurrent-part
    int p = (idx - OFF_R12A) >> 6;
    int wv = p / 12; mat = (p / 4) % 3; int kt = p & 3;
    ld = CAT1; n = wv * 16 + col; nmax = Nc; k0 = Ni + kt * 32 + q * 8; kmax = CAT1;
    if (mat == 0) Wa = w1_1;
    else if (mat == 1) Wa = w2_1;
    else { Wa = wa_1; Wb = wb_1; }
  } else {  // r12 layer2 (full cat)
    int p = (idx - OFF_R12B) >> 6;
    mat = p / 4; int kt = p & 3;
    ld = CAT2; n = col; nmax = Nm; k0 = kt * 32 + q * 8; kmax = CAT2;
    if (mat == 0) { Wa = w1_2; M = m2; }
    else if (mat == 1) { Wa = w2_2; M = m2; }
    else { Wa = wa_2; Wb = wb_2; }
  }
  h8 r;
#pragma unroll
  for (int j = 0; j < 8; j++) {
    int k = k0 + j;
    float v = 0.f;
    if (n < nmax && k < kmax) {
      if (mat < 2) {
        v = Wa[(size_t)n * ld + k];
        if (M) v *= (float)M[(size_t)n * ld + k];
        v *= -2.f * L2E;                 // ff pre-scale: acc = -2u*log2(e)
      } else {
        v = -L2E * (ts * Wa[(size_t)n * ld + k] + Wb[(size_t)n * ld + k]);
      }
    }
    r[j] = (f16)v;
  }
  ((h8*)PK)[idx] = r;
}

// ------- r0 one step: consume xu (t), reload xu for t+4 (depth-4 pipeline) -----------
__device__ __forceinline__ void r0_step(
    const f16* br, f16* bw, const f16* __restrict__ XU0, f16* __restrict__ NH0,
    float* __restrict__ out, const h8 (&Bf)[3][5], h4 (&xu)[3],
    int t, int tload, int bt, int g, int lane, int col, int q, int n, bool last) {
  h8 A[5];
#pragma unroll
  for (int kt = 0; kt < 5; kt++)
    A[kt] = *(const h8*)(br + col * S0 + kt * 32 + q * 8);
  f4 acc0 = {(float)xu[0][0], (float)xu[0][1], (float)xu[0][2], (float)xu[0][3]};
  f4 acc1 = {(float)xu[1][0], (float)xu[1][1], (float)xu[1][2], (float)xu[1][3]};
  f4 acc2 = {(float)xu[2][0], (float)xu[2][1], (float)xu[2][2], (float)xu[2][3]};
  size_t mtl = (size_t)tload * NBT + bt;
#pragma unroll
  for (int mat = 0; mat < 3; mat++)
    xu[mat] = *(const h4*)(XU0 + (mtl * NT0 + mat * 10 + g) * 256 + lane * 4);
#pragma unroll
  for (int kt = 0; kt < 5; kt++) {
    acc0 = MFMA(A[kt], Bf[0][kt], acc0);
    acc1 = MFMA(A[kt], Bf[1][kt], acc1);
    acc2 = MFMA(A[kt], Bf[2][kt], acc2);
  }
  int mt = t * NBT + bt;
  f16* nh = NH0 + (size_t)mt * 2560;
#pragma unroll
  for (int r = 0; r < 4; r++) {
    int m = q * 4 + r;
    float h = cfc_h(acc0[r], acc1[r], acc2[r]);
    f16 h16 = (f16)h;
    bw[m * S0 + n] = h16;
    nh[m * 160 + n] = h16;   // cols >= Ni are exact zeros (zero weights+bias)
    if (last && n < Ni) out[YOFF + (size_t)(bt * 16 + m) * 256 + n] = h;
  }
}

// ------- r12 layer1 one step: consume xu(t), reload xu for t+2 -----------------------
__device__ __forceinline__ void r12l1_step(
    const f16* br, f16* bw, const f16* __restrict__ XU1, float* __restrict__ out,
    const h8 (&Bf)[3][4], h4 (&xu)[3],
    int tload, int bt, int w, int lane, int col, int q, int n, bool last) {
  h8 A[4];
#pragma unroll
  for (int kt = 0; kt < 4; kt++)
    A[kt] = *(const h8*)(br + col * S2 + kt * 32 + q * 8);
  f4 acc0 = {(float)xu[0][0], (float)xu[0][1], (float)xu[0][2], (float)xu[0][3]};
  f4 acc1 = {(float)xu[1][0], (float)xu[1][1], (float)xu[1][2], (float)xu[1][3]};
  f4 acc2 = {(float)xu[2][0], (float)xu[2][1], (float)xu[2][2], (float)xu[2][3]};
  size_t mtl = (size_t)tload * NBT + bt;
#pragma unroll
  for (int mat = 0; mat < 3; mat++)
    xu[mat] = *(const h4*)(XU1 + (mtl * NT1 + mat * 7 + w) * 256 + lane * 4);
#pragma unroll
  for (int kt = 0; kt < 4; kt++) {
    acc0 = MFMA(A[kt], Bf[0][kt], acc0);
    acc1 = MFMA(A[kt], Bf[1][kt], acc1);
    acc2 = MFMA(A[kt], Bf[2][kt], acc2);
  }
#pragma unroll
  for (int r = 0; r < 4; r++) {
    int m = q * 4 + r;
    float h = cfc_h(acc0[r], acc1[r], acc2[r]);
    if (n < Nc) {
      bw[m * S2 + n] = (f16)h;
      if (last) out[YOFF + (size_t)(bt * 16 + m) * 256 + Ni + n] = h;
    }
  }
}

// ------- r12 layer2 one step: reads rb (nh1(t)|h2(t-1)), writes h2(t) into wb --------
__device__ __forceinline__ void r12l2_step(
    const f16* rb, f16* wb, float* __restrict__ out, const h8 (&Bf)[3][4],
    float bn0, float bn1, float bn2, int tg, int bt, int col, int q, bool last) {
  h8 A[4];
#pragma unroll
  for (int kt = 0; kt < 4; kt++)
    A[kt] = *(const h8*)(rb + col * S2 + kt * 32 + q * 8);
  f4 acc0 = {bn0, bn0, bn0, bn0};
  f4 acc1 = {bn1, bn1, bn1, bn1};
  f4 acc2 = {bn2, bn2, bn2, bn2};
#pragma unroll
  for (int kt = 0; kt < 4; kt++) {
    acc0 = MFMA(A[kt], Bf[0][kt], acc0);
    acc1 = MFMA(A[kt], Bf[1][kt], acc1);
    acc2 = MFMA(A[kt], Bf[2][kt], acc2);
  }
#pragma unroll
  for (int r = 0; r < 4; r++) {
    int m = q * 4 + r;
    float h = cfc_h(acc0[r], acc1[r], acc2[r]);
    if (col < Nm) {
      out[((size_t)(bt * 16 + m) * Tsz + tg) * 8 + col] = tanhp_(h);
      wb[m * S2 + Nc + col] = (f16)h;
      if (last) out[YOFF + (size_t)(bt * 16 + m) * 256 + Ni + Nc + col] = h;
    }
  }
}

// ---- persistent kernel: pack; phases ph=-1..NCH+1 with grid.sync between ------------
// WG roles: [r0(ph) 0-15 | r12(ph-2) 16-31 | x1(ph-1) 32-95 | x0(ph+1) 96-223]
__global__ __launch_bounds__(640) void cfc_kernel(
    f16* __restrict__ PK,
    const float* __restrict__ w1_0, const float* __restrict__ w2_0,
    const float* __restrict__ wa_0, const float* __restrict__ wb_0,
    const int* __restrict__ m0,
    const float* __restrict__ b1_0, const float* __restrict__ b2_0,
    const float* __restrict__ ba_0, const float* __restrict__ bb_0,
    const float* __restrict__ w1_1, const float* __restrict__ w2_1,
    const float* __restrict__ wa_1, const float* __restrict__ wb_1,
    const int* __restrict__ m1,
    const float* __restrict__ b1_1, const float* __restrict__ b2_1,
    const float* __restrict__ ba_1, const float* __restrict__ bb_1,
    const float* __restrict__ w1_2, const float* __restrict__ w2_2,
    const float* __restrict__ wa_2, const float* __restrict__ wb_2,
    const int* __restrict__ m2,
    const float* __restrict__ c1, const float* __restrict__ c2,
    const float* __restrict__ ca, const float* __restrict__ cb,
    const float* __restrict__ dtp, const float* __restrict__ x,
    f16* __restrict__ XU0, f16* __restrict__ NH0, f16* __restrict__ XU1,
    float* __restrict__ out) {
  __shared__ __align__(16) char smem[10752];  // union: r0 10752 / r12 8704 / x0 4352
  cg::grid_group grid = cg::this_grid();
  int tid = threadIdx.x;
  int g = tid >> 6, lane = tid & 63, col = lane & 15, q = lane >> 4;
  int wg = blockIdx.x;
  float ts = dtp[0];
  const h8* pk = (const h8*)PK;

  // ---- phase -2: pack (one thread per fragment) ----
  {
    int gtid = wg * 640 + tid;
    if (gtid < NFRAG)
      pack_one(gtid, w1_0, w2_0, wa_0, wb_0, m0, w1_1, w2_1, wa_1, wb_1, m1,
               w1_2, w2_2, wa_2, wb_2, m2, ts, PK);
  }
  grid.sync();

  if (wg < NBT) {  // ================= r0, chunk = ph =================
    f16(*buf)[16 * S0] = (f16(*)[16 * S0])smem;
    int bt = wg;
    int n = g * 16 + col;                      // output neuron (0..159, valid <149)
    h8 Bf[3][5];                               // recurrent weights, resident all run
#pragma unroll
    for (int mat = 0; mat < 3; mat++)
#pragma unroll
      for (int kt = 0; kt < 5; kt++)
        Bf[mat][kt] = pk[OFF_R0 + ((g * 3 + mat) * 5 + kt) * 64 + lane];
    for (int idx = tid; idx < 2 * 16 * S0; idx += 640) ((f16*)buf)[idx] = (f16)0.f;
    __syncthreads();

    for (int ph = -1; ph <= NCH + 1; ++ph) {
      if (ph >= 0 && ph < NCH) {
        int c = ph;
        const f16* XU0r = XU0 + (size_t)(c & 1) * XU0C;
        f16* NH0w = NH0 + (size_t)(c & 1) * NH0C;
        h4 xu0[3], xu1[3], xu2[3], xu3[3];     // depth-4 prefetch (2-step lead)
#pragma unroll
        for (int mat = 0; mat < 3; mat++) {
          xu0[mat] = *(const h4*)(XU0r + ((size_t)(0 * NBT + bt) * NT0 + mat * 10 + g) * 256 + lane * 4);
          xu1[mat] = *(const h4*)(XU0r + ((size_t)(1 * NBT + bt) * NT0 + mat * 10 + g) * 256 + lane * 4);
          xu2[mat] = *(const h4*)(XU0r + ((size_t)(2 * NBT + bt) * NT0 + mat * 10 + g) * 256 + lane * 4);
          xu3[mat] = *(const h4*)(XU0r + ((size_t)(3 * NBT + bt) * NT0 + mat * 10 + g) * 256 + lane * 4);
        }
        for (int t = 0; t < TC; t += 4) {
          r0_step(buf[0], buf[1], XU0r, NH0w, out, Bf, xu0, t,
                  (t + 4 < TC) ? t + 4 : t, bt, g, lane, col, q, n, false);
          RAW_BAR();
          r0_step(buf[1], buf[0], XU0r, NH0w, out, Bf, xu1, t + 1,
                  (t + 5 < TC) ? t + 5 : t + 1, bt, g, lane, col, q, n, false);
          RAW_BAR();
          r0_step(buf[0], buf[1], XU0r, NH0w, out, Bf, xu2, t + 2,
                  (t + 6 < TC) ? t + 6 : t + 2, bt, g, lane, col, q, n, false);
          RAW_BAR();
          bool lastD = (c == NCH - 1) && (t + 3 == TC - 1);
          r0_step(buf[1], buf[0], XU0r, NH0w, out, Bf, xu3, t + 3,
                  (t + 7 < TC) ? t + 7 : t + 3, bt, g, lane, col, q, n, lastD);
          RAW_BAR();
        }
      }
      if (ph <= NCH) grid.sync();
    }

  } else if (wg < 2 * NBT) {  // ================= r12, chunk = ph-2 =================
    f16(*buf)[16 * S2] = (f16(*)[16 * S2])smem;
    int bt = wg - NBT;
    int w = g;                                 // wave id 0..9 (8,9 barrier-only)
    int n = w * 16 + col;
    h8 Bf[3][4];
    float bn0 = 0.f, bn1 = 0.f, bn2 = 0.f;
    if (w < 7) {
#pragma unroll
      for (int mat = 0; mat < 3; mat++)
#pragma unroll
        for (int kt = 0; kt < 4; kt++)
          Bf[mat][kt] = pk[OFF_R12A + ((w * 3 + mat) * 4 + kt) * 64 + lane];
    } else if (w == 7) {
#pragma unroll
      for (int mat = 0; mat < 3; mat++)
#pragma unroll
        for (int kt = 0; kt < 4; kt++)
          Bf[mat][kt] = pk[OFF_R12B + (mat * 4 + kt) * 64 + lane];
      bn0 = (col < Nm) ? -2.f * L2E * c1[col] : 0.f;
      bn1 = (col < Nm) ? -2.f * L2E * c2[col] : 0.f;
      bn2 = (col < Nm) ? -L2E * (ts * ca[col] + cb[col]) : 0.f;
    }
    for (int idx = tid; idx < 2 * 16 * S2; idx += 640) ((f16*)buf)[idx] = (f16)0.f;
    __syncthreads();

    for (int ph = -1; ph <= NCH + 1; ++ph) {
      int cc = ph - 2;
      if (cc >= 0 && cc < NCH) {
        const f16* XU1r = XU1 + (size_t)(cc & 1) * XU1C;
        h4 xuA[3], xuB[3];                     // depth-2 prefetch register sets
        if (w < 7) {
#pragma unroll
          for (int mat = 0; mat < 3; mat++) {
            xuA[mat] = *(const h4*)(XU1r + ((size_t)bt * NT1 + mat * 7 + w) * 256 + lane * 4);
            xuB[mat] = *(const h4*)(XU1r +
                                    ((size_t)(NBT + bt) * NT1 + mat * 7 + w) * 256 + lane * 4);
          }
        }
        for (int t = 0; t < TC; t += 2) {
          if (w < 7) {
            int tlA = (t + 2 < TC) ? t + 2 : t;
            r12l1_step(buf[0], buf[1], XU1r, out, Bf, xuA, tlA, bt, w, lane, col, q,
                       n, false);                           // last never hits even t
          }
          RAW_BAR();
          if (w == 7)
            r12l2_step(buf[1], buf[0], out, Bf, bn0, bn1, bn2, cc * TC + t, bt, col,
                       q, false);
          if (w < 7) {
            int tlB = (t + 3 < TC) ? t + 3 : t + 1;
            bool lastB = (cc == NCH - 1) && (t + 1 == TC - 1);
            r12l1_step(buf[1], buf[0], XU1r, out, Bf, xuB, tlB, bt, w, lane, col, q,
                       n, lastB);
          }
          RAW_BAR();
          if (w == 7)
            r12l2_step(buf[0], buf[1], out, Bf, bn0, bn1, bn2, cc * TC + t + 1, bt,
                       col, q, (cc == NCH - 1) && (t + 1 == TC - 1));
        }
      }
      if (ph <= NCH) grid.sync();
    }

  } else if (wg < 2 * NBT + NXWG1) {  // ========= x1, chunk = ph-1 (bulk) =========
    int bx = wg - 2 * NBT;                     // 0..NXWG1-1
    int w = g;                                 // waves 0-6 active, 7-9 idle
    int n = w * 16 + col;
    h8 Bf[3][5];
    float bias[3] = {0.f, 0.f, 0.f};
    if (w < 7) {
#pragma unroll
      for (int mat = 0; mat < 3; mat++)
#pragma unroll
        for (int kt = 0; kt < 5; kt++)
          Bf[mat][kt] = pk[OFF_X1 + (mat * 35 + w * 5 + kt) * 64 + lane];
      bias[0] = (n < Nc) ? -2.f * L2E * b1_1[n] : 0.f;
      bias[1] = (n < Nc) ? -2.f * L2E * b2_1[n] : 0.f;
      bias[2] = (n < Nc) ? -L2E * (ts * ba_1[n] + bb_1[n]) : 0.f;
    }
    for (int ph = -1; ph <= NCH + 1; ++ph) {
      int cx = ph - 1;
      if (w < 7 && cx >= 0 && cx < NCH) {
        const f16* NH0r = NH0 + (size_t)(cx & 1) * NH0C;
        f16* XU1w = XU1 + (size_t)(cx & 1) * XU1C;
        for (int i = 0; i < (TC * NBT) / NXWG1; i++) {   // 16 mt tiles per WG
          int mt = bx * ((TC * NBT) / NXWG1) + i;
          const f16* Ab = NH0r + (size_t)mt * 2560;      // 16x160 halves, zero-padded
          h8 A[5];
#pragma unroll
          for (int kt = 0; kt < 5; kt++)
            A[kt] = *(const h8*)(Ab + col * 160 + kt * 32 + q * 8);
#pragma unroll
          for (int mat = 0; mat < 3; mat++) {
            float b = bias[mat];
            f4 acc = {b, b, b, b};
#pragma unroll
            for (int kt = 0; kt < 5; kt++) acc = MFMA(A[kt], Bf[mat][kt], acc);
            h4 o;
#pragma unroll
            for (int rr = 0; rr < 4; rr++) o[rr] = (f16)acc[rr];
            *(h4*)(XU1w + ((size_t)mt * NT1 + mat * 7 + w) * 256 + lane * 4) = o;
          }
        }
      }
      if (ph <= NCH) grid.sync();
    }

  } else {  // ================= x0, chunk = ph+1 (no recurrence dep) ================
    f16* stg = (f16*)smem;                     // 16 x 136
    int bx = wg - 2 * NBT - NXWG1;             // 0..NXWG0-1
    int w = g;                                 // wave -> output tile g=w, all 3 mats
    int n = w * 16 + col;
    h8 Bx[3][4];
    float bias[3];
#pragma unroll
    for (int mat = 0; mat < 3; mat++)
#pragma unroll
      for (int kt = 0; kt < 4; kt++)
        Bx[mat][kt] = pk[OFF_X0 + ((mat * 10 + w) * 4 + kt) * 64 + lane];
    bias[0] = (n < Ni) ? -2.f * L2E * b1_0[n] : 0.f;
    bias[1] = (n < Ni) ? -2.f * L2E * b2_0[n] : 0.f;
    bias[2] = (n < Ni) ? -L2E * (ts * ba_0[n] + bb_0[n]) : 0.f;
    for (int ph = -1; ph <= NCH + 1; ++ph) {
      int cn = ph + 1;
      if (cn >= 0 && cn < NCH) {
        f16* XU0w = XU0 + (size_t)(cn & 1) * XU0C;
        for (int i = 0; i < (TC * NBT) / NXWG0; i++) {   // 8 mt tiles per WG
          int mt = bx * ((TC * NBT) / NXWG0) + i;
          int tl = mt >> 4, bt = mt & 15;
          int tg = cn * TC + tl;
          if (tid < 256) {
            int sr = tid >> 4, sc = (tid & 15) * 8;
            const float* xp = x + ((size_t)(bt * 16 + sr) * Tsz + tg) * IN_DIM + sc;
            h8 hv;
#pragma unroll
            for (int j = 0; j < 8; j++) hv[j] = (f16)xp[j];
            *(h8*)(stg + sr * 136 + sc) = hv;
          }
          __syncthreads();
          h8 A[4];
#pragma unroll
          for (int kt = 0; kt < 4; kt++)
            A[kt] = *(const h8*)(stg + col * 136 + kt * 32 + q * 8);
#pragma unroll
          for (int mat = 0; mat < 3; mat++) {
            float b = bias[mat];
            f4 acc = {b, b, b, b};
#pragma unroll
            for (int kt = 0; kt < 4; kt++) acc = MFMA(A[kt], Bx[mat][kt], acc);
            h4 o;
#pragma unroll
            for (int rr = 0; rr < 4; rr++) o[rr] = (f16)acc[rr];
            *(h4*)(XU0w + ((size_t)mt * NT0 + mat * 10 + w) * 256 + lane * 4) = o;
          }
          __syncthreads();
        }
      }
      if (ph <= NCH) grid.sync();
    }
  }
}

extern "C" void kernel_launch(void* const* d_in, const int* in_sizes, int n_in,
                              void* d_out, int out_size, void* d_ws, size_t ws_size,
                              hipStream_t stream) {
  const float* w1_0 = (const float*)d_in[0];
  const float* w2_0 = (const float*)d_in[1];
  const float* wa_0 = (const float*)d_in[2];
  const float* wb_0 = (const float*)d_in[3];
  const float* b1_0 = (const float*)d_in[4];
  const float* b2_0 = (const float*)d_in[5];
  const float* ba_0 = (const float*)d_in[6];
  const float* bb_0 = (const float*)d_in[7];
  const int* m0 = (const int*)d_in[8];
  const float* w1_1 = (const float*)d_in[9];
  const float* w2_1 = (const float*)d_in[10];
  const float* wa_1 = (const float*)d_in[11];
  const float* wb_1 = (const float*)d_in[12];
  const float* b1_1 = (const float*)d_in[13];
  const float* b2_1 = (const float*)d_in[14];
  const float* ba_1 = (const float*)d_in[15];
  const float* bb_1 = (const float*)d_in[16];
  const int* m1 = (const int*)d_in[17];
  const float* w1_2 = (const float*)d_in[18];
  const float* w2_2 = (const float*)d_in[19];
  const float* wa_2 = (const float*)d_in[20];
  const float* wb_2 = (const float*)d_in[21];
  const float* c1 = (const float*)d_in[22];
  const float* c2 = (const float*)d_in[23];
  const float* ca = (const float*)d_in[24];
  const float* cb = (const float*)d_in[25];
  const int* m2 = (const int*)d_in[26];
  const float* x = (const float*)d_in[27];
  const float* dt = (const float*)d_in[28];
  float* out = (float*)d_out;

  f16* XU0 = (f16*)d_ws;                 // 2 x XU0C
  f16* NH0 = XU0 + 2 * XU0C;             // 2 x NH0C
  f16* XU1 = NH0 + 2 * NH0C;             // 2 x XU1C
  f16* PK = XU1 + 2 * XU1C;

  void* args[] = {
      &PK,
      &w1_0, &w2_0, &wa_0, &wb_0, &m0, &b1_0, &b2_0, &ba_0, &bb_0,
      &w1_1, &w2_1, &wa_1, &wb_1, &m1, &b1_1, &b2_1, &ba_1, &bb_1,
      &w1_2, &w2_2, &wa_2, &wb_2, &m2,
      &c1, &c2, &ca, &cb,
      &dt, &x,
      &XU0, &NH0, &XU1,
      &out};
  hipLaunchCooperativeKernel((void*)cfc_kernel, dim3(NWG), dim3(640), args, 0,
                             stream);
}

// Round 5
// 732.839 us; speedup vs baseline: 2.2104x; 1.3705x over previous
//
#include <hip/hip_runtime.h>
#include <cmath>

// CfC-NCP RNN, phase-decomposed + chunk-pipelined.
// R10: R7 multi-launch structure (772 us, proven) with r12 moved from lag-2 to
// lag-1 via an intra-launch x1->r12 handshake (saves one ~70 us slot):
//  - launch c runs [ r0(c) | r12(c-1) | x1(c-1) | x0(c+1) ].
//  - x1 WGs (64) each produce one time-step of XU1(c-1) from NH0(c-1) (safe:
//    NH0(c-1) finished at the previous kernel boundary), then
//    release-atomicAdd CNT[c-1] at agent scope.
//  - r12 WGs spin once per chunk until CNT[cc]==64, then acquire-fence (agent)
//    so XU1 lines (possibly stale in this XCD's L2 from 2 chunks ago) refetch.
//    Spin is bounded (no hang) and hidden: x1 completes in ~15 us, r12 stepping
//    needs ~55 us, r0 paces the slot at ~67 us.
//  - Chain: pack; R(-1)[x0(0)]; R(0..7)[all]; R(8)[x1(7)|r12(7)] = 10 slots.
// R9 lesson: grid.sync() ~15 us/phase on 224 WGs — worse than kernel
// boundaries. R8 lesson: l1 cannot hold 108 resident weight VGPRs (allocator
// remats weight loads into the loop) -> r12 stays recurrent-only, x1 stays bulk.
// Carried: packed weights, merged -(ts*wa+wb), -2*log2e pre-scale, depth-4 r0
// xu prefetch, depth-2 r12 xu prefetch, raw lgkmcnt-only barriers, single-rcp
// exp2 epilogue.

typedef _Float16 f16;
typedef f16 h4 __attribute__((ext_vector_type(4)));
typedef f16 h8 __attribute__((ext_vector_type(8)));
typedef float f4 __attribute__((ext_vector_type(4)));

#define MFMA(a, b, c) __builtin_amdgcn_mfma_f32_16x16x32_f16(a, b, c, 0, 0, 0)
#define RAW_BAR() asm volatile("s_waitcnt lgkmcnt(0)\n\ts_barrier" ::: "memory")

constexpr int IN_DIM = 128, Ni = 149, Nc = 99, Nm = 8;
constexpr int CAT0 = 277, CAT1 = 248, CAT2 = 107;
constexpr int Bsz = 256, Tsz = 512;
constexpr int TC = 64, NCH = 8, NBT = 16;
constexpr int NT0 = 30, NT1 = 21;        // fragment tile-columns (3 mats x n-tiles)
constexpr int S0 = 168, S2 = 136;        // LDS row strides (halves), bank-conflict pad
constexpr int NXWG1 = 64;                // x1 workgroups per R launch
constexpr int NXWG0 = 128;               // x0 workgroups per R launch
constexpr size_t XU0C = (size_t)TC * NBT * NT0 * 256;  // 7,864,320 halves / buffer
constexpr size_t NH0C = (size_t)TC * NBT * 2560;       // 2,621,440 halves / buffer
constexpr size_t XU1C = (size_t)TC * NBT * NT1 * 256;  // 5,505,024 halves / buffer
constexpr size_t H0S_HALVES = (size_t)NBT * 16 * S0;
constexpr size_t H12S_HALVES = (size_t)NBT * 2 * 16 * S2;
constexpr size_t YOFF = (size_t)Bsz * Tsz * 8;  // h_out offset in d_out
constexpr float L2E = 1.4426950408889634f;      // log2(e), folded into weights

// packed-fragment segment offsets (h8 units); mat2 = merged -(ts*wa+wb)
constexpr int OFF_X0 = 0;          // [mat3][nt10][kt4][lane64]
constexpr int OFF_R0 = 7680;       // [g10][mat3][kt5][lane64]
constexpr int OFF_X1 = 17280;      // [mat3][nt7][kt5][lane64]
constexpr int OFF_R12A = 24000;    // [w7][mat3][kt4][lane64]
constexpr int OFF_R12B = 29376;    // [mat3][kt4][lane64]
constexpr int NFRAG = 30144;

__device__ inline float rcpf_(float x) { return __builtin_amdgcn_rcpf(x); }
__device__ __forceinline__ float exp2p_(float x) {
#if __has_builtin(__builtin_amdgcn_exp2f)
  return __builtin_amdgcn_exp2f(x);
#else
  return exp2f(x);
#endif
}
// h = ff1 + (ff2-ff1)*ti with ff=(1-e)/(1+e), ti=1/(1+c).
// a0=-2u1*L2E, a1=-2u2*L2E, a2=-z*L2E (scales pre-folded into weights/biases).
__device__ __forceinline__ float cfc_h(float a0, float a1, float a2) {
  float e0 = exp2p_(a0), e1 = exp2p_(a1), e2 = exp2p_(a2);
  float pa = 1.f + e0, ma = 1.f - e0;
  float pb = 1.f + e1, mb = 1.f - e1;
  float pc = 1.f + e2;
  float num = fmaf(ma * pb, e2, mb * pa);
  return num * rcpf_(pa * pb * pc);
}
__device__ __forceinline__ float tanhp_(float x) {  // tanh(x)
  float e = exp2p_(-2.f * L2E * x);
  return (1.f - e) * rcpf_(1.f + e);
}

// ---------------- pack: build all h8 weight fragments once per call ------------------
__global__ __launch_bounds__(256) void pack_kernel(
    const float* __restrict__ w1_0, const float* __restrict__ w2_0,
    const float* __restrict__ wa_0, const float* __restrict__ wb_0,
    const int* __restrict__ m0,
    const float* __restrict__ w1_1, const float* __restrict__ w2_1,
    const float* __restrict__ wa_1, const float* __restrict__ wb_1,
    const int* __restrict__ m1,
    const float* __restrict__ w1_2, const float* __restrict__ w2_2,
    const float* __restrict__ wa_2, const float* __restrict__ wb_2,
    const int* __restrict__ m2, const float* __restrict__ dtp,
    f16* __restrict__ PK, int* __restrict__ CNT) {
  if (blockIdx.x == 0 && threadIdx.x < NCH)
    __hip_atomic_store(&CNT[threadIdx.x], 0, __ATOMIC_RELAXED,
                       __HIP_MEMORY_SCOPE_AGENT);
  int idx = blockIdx.x * 256 + threadIdx.x;
  if (idx >= NFRAG) return;
  int lane = idx & 63, col = lane & 15, q = lane >> 4;
  float ts = dtp[0];
  const float* Wa = nullptr;
  const float* Wb = nullptr;
  const int* M = nullptr;
  int ld, n, nmax, k0, kmax;
  int mat;
  if (idx < OFF_R0) {  // x0 input-part
    int p = idx >> 6;
    mat = p / 40; int nt = (p >> 2) % 10, kt = p & 3;
    ld = CAT0; n = nt * 16 + col; nmax = Ni; k0 = kt * 32 + q * 8; kmax = IN_DIM;
    if (mat == 0) { Wa = w1_0; M = m0; }
    else if (mat == 1) { Wa = w2_0; M = m0; }
    else { Wa = wa_0; Wb = wb_0; }
  } else if (idx < OFF_X1) {  // r0 recurrent-part
    int p = (idx - OFF_R0) >> 6;
    int g = p / 15; mat = (p / 5) % 3; int kt = p % 5;
    ld = CAT0; n = g * 16 + col; nmax = Ni; k0 = IN_DIM + kt * 32 + q * 8; kmax = CAT0;
    if (mat == 0) Wa = w1_0;
    else if (mat == 1) Wa = w2_0;
    else { Wa = wa_0; Wb = wb_0; }
  } else if (idx < OFF_R12A) {  // x1 input-part
    int p = (idx - OFF_X1) >> 6;
    mat = p / 35; int nt = (p / 5) % 7, kt = p % 5;
    ld = CAT1; n = nt * 16 + col; nmax = Nc; k0 = kt * 32 + q * 8; kmax = Ni;
    if (mat == 0) { Wa = w1_1; M = m1; }
    else if (mat == 1) { Wa = w2_1; M = m1; }
    else { Wa = wa_1; Wb = wb_1; }
  } else if (idx < OFF_R12B) {  // r12 layer1 recurrent-part
    int p = (idx - OFF_R12A) >> 6;
    int wv = p / 12; mat = (p / 4) % 3; int kt = p & 3;
    ld = CAT1; n = wv * 16 + col; nmax = Nc; k0 = Ni + kt * 32 + q * 8; kmax = CAT1;
    if (mat == 0) Wa = w1_1;
    else if (mat == 1) Wa = w2_1;
    else { Wa = wa_1; Wb = wb_1; }
  } else {  // r12 layer2 (full cat)
    int p = (idx - OFF_R12B) >> 6;
    mat = p / 4; int kt = p & 3;
    ld = CAT2; n = col; nmax = Nm; k0 = kt * 32 + q * 8; kmax = CAT2;
    if (mat == 0) { Wa = w1_2; M = m2; }
    else if (mat == 1) { Wa = w2_2; M = m2; }
    else { Wa = wa_2; Wb = wb_2; }
  }
  h8 r;
#pragma unroll
  for (int j = 0; j < 8; j++) {
    int k = k0 + j;
    float v = 0.f;
    if (n < nmax && k < kmax) {
      if (mat < 2) {
        v = Wa[(size_t)n * ld + k];
        if (M) v *= (float)M[(size_t)n * ld + k];
        v *= -2.f * L2E;                 // ff pre-scale: acc = -2u*log2(e)
      } else {
        v = -L2E * (ts * Wa[(size_t)n * ld + k] + Wb[(size_t)n * ld + k]);
      }
    }
    r[j] = (f16)v;
  }
  ((h8*)PK)[idx] = r;
}

// ------- r0 one step: consume xu (t), reload xu for t+4 (depth-4 pipeline) -----------
__device__ __forceinline__ void r0_step(
    const f16* br, f16* bw, const f16* __restrict__ XU0, f16* __restrict__ NH0,
    float* __restrict__ out, const h8 (&Bf)[3][5], h4 (&xu)[3],
    int t, int tload, int bt, int g, int lane, int col, int q, int n, bool last) {
  h8 A[5];
#pragma unroll
  for (int kt = 0; kt < 5; kt++)
    A[kt] = *(const h8*)(br + col * S0 + kt * 32 + q * 8);
  f4 acc0 = {(float)xu[0][0], (float)xu[0][1], (float)xu[0][2], (float)xu[0][3]};
  f4 acc1 = {(float)xu[1][0], (float)xu[1][1], (float)xu[1][2], (float)xu[1][3]};
  f4 acc2 = {(float)xu[2][0], (float)xu[2][1], (float)xu[2][2], (float)xu[2][3]};
  size_t mtl = (size_t)tload * NBT + bt;
#pragma unroll
  for (int mat = 0; mat < 3; mat++)
    xu[mat] = *(const h4*)(XU0 + (mtl * NT0 + mat * 10 + g) * 256 + lane * 4);
#pragma unroll
  for (int kt = 0; kt < 5; kt++) {
    acc0 = MFMA(A[kt], Bf[0][kt], acc0);
    acc1 = MFMA(A[kt], Bf[1][kt], acc1);
    acc2 = MFMA(A[kt], Bf[2][kt], acc2);
  }
  int mt = t * NBT + bt;
  f16* nh = NH0 + (size_t)mt * 2560;
#pragma unroll
  for (int r = 0; r < 4; r++) {
    int m = q * 4 + r;
    float h = cfc_h(acc0[r], acc1[r], acc2[r]);
    f16 h16 = (f16)h;
    bw[m * S0 + n] = h16;
    nh[m * 160 + n] = h16;   // cols >= Ni are exact zeros (zero weights+bias)
    if (last && n < Ni) out[YOFF + (size_t)(bt * 16 + m) * 256 + n] = h;
  }
}

// ------- r12 layer1 one step: consume xu(t), reload xu for t+2 -----------------------
__device__ __forceinline__ void r12l1_step(
    const f16* br, f16* bw, const f16* __restrict__ XU1, float* __restrict__ out,
    const h8 (&Bf)[3][4], h4 (&xu)[3],
    int tload, int bt, int w, int lane, int col, int q, int n, bool last) {
  h8 A[4];
#pragma unroll
  for (int kt = 0; kt < 4; kt++)
    A[kt] = *(const h8*)(br + col * S2 + kt * 32 + q * 8);
  f4 acc0 = {(float)xu[0][0], (float)xu[0][1], (float)xu[0][2], (float)xu[0][3]};
  f4 acc1 = {(float)xu[1][0], (float)xu[1][1], (float)xu[1][2], (float)xu[1][3]};
  f4 acc2 = {(float)xu[2][0], (float)xu[2][1], (float)xu[2][2], (float)xu[2][3]};
  size_t mtl = (size_t)tload * NBT + bt;
#pragma unroll
  for (int mat = 0; mat < 3; mat++)
    xu[mat] = *(const h4*)(XU1 + (mtl * NT1 + mat * 7 + w) * 256 + lane * 4);
#pragma unroll
  for (int kt = 0; kt < 4; kt++) {
    acc0 = MFMA(A[kt], Bf[0][kt], acc0);
    acc1 = MFMA(A[kt], Bf[1][kt], acc1);
    acc2 = MFMA(A[kt], Bf[2][kt], acc2);
  }
#pragma unroll
  for (int r = 0; r < 4; r++) {
    int m = q * 4 + r;
    float h = cfc_h(acc0[r], acc1[r], acc2[r]);
    if (n < Nc) {
      bw[m * S2 + n] = (f16)h;
      if (last) out[YOFF + (size_t)(bt * 16 + m) * 256 + Ni + n] = h;
    }
  }
}

// ------- r12 layer2 one step: reads rb (nh1(t)|h2(t-1)), writes h2(t) into wb --------
__device__ __forceinline__ void r12l2_step(
    const f16* rb, f16* wb, float* __restrict__ out, const h8 (&Bf)[3][4],
    float bn0, float bn1, float bn2, int tg, int bt, int col, int q, bool last) {
  h8 A[4];
#pragma unroll
  for (int kt = 0; kt < 4; kt++)
    A[kt] = *(const h8*)(rb + col * S2 + kt * 32 + q * 8);
  f4 acc0 = {bn0, bn0, bn0, bn0};
  f4 acc1 = {bn1, bn1, bn1, bn1};
  f4 acc2 = {bn2, bn2, bn2, bn2};
#pragma unroll
  for (int kt = 0; kt < 4; kt++) {
    acc0 = MFMA(A[kt], Bf[0][kt], acc0);
    acc1 = MFMA(A[kt], Bf[1][kt], acc1);
    acc2 = MFMA(A[kt], Bf[2][kt], acc2);
  }
#pragma unroll
  for (int r = 0; r < 4; r++) {
    int m = q * 4 + r;
    float h = cfc_h(acc0[r], acc1[r], acc2[r]);
    if (col < Nm) {
      out[((size_t)(bt * 16 + m) * Tsz + tg) * 8 + col] = tanhp_(h);
      wb[m * S2 + Nc + col] = (f16)h;
      if (last) out[YOFF + (size_t)(bt * 16 + m) * 256 + Ni + Nc + col] = h;
    }
  }
}

// ---- R: [r0(c) 0-15 | r12(c-1) 16-31 | x1(c-1) 32-95 | x0(c+1) 96-223] --------------
__global__ __launch_bounds__(640) void R_kernel(
    const h8* __restrict__ pk,
    const float* __restrict__ b1_0, const float* __restrict__ b2_0,
    const float* __restrict__ ba_0, const float* __restrict__ bb_0,
    const float* __restrict__ b1_1, const float* __restrict__ b2_1,
    const float* __restrict__ ba_1, const float* __restrict__ bb_1,
    const float* __restrict__ c1, const float* __restrict__ c2,
    const float* __restrict__ ca, const float* __restrict__ cb,
    const float* __restrict__ dtp, const float* __restrict__ x,
    f16* __restrict__ XU0, f16* __restrict__ NH0, f16* __restrict__ XU1,
    f16* __restrict__ H0S, f16* __restrict__ H12S,
    int* __restrict__ CNT, float* __restrict__ out, int c) {
  __shared__ __align__(16) char smem[10752];  // union: r0 10752 / r12 8704 / x0 4352
  int tid = threadIdx.x;
  int g = tid >> 6, lane = tid & 63, col = lane & 15, q = lane >> 4;
  int wg = blockIdx.x;
  float ts = dtp[0];

  if (wg < NBT) {  // ================= r0, chunk c =================
    if (c < 0 || c >= NCH) return;
    const f16* XU0r = XU0 + (size_t)(c & 1) * XU0C;
    f16* NH0w = NH0 + (size_t)(c & 1) * NH0C;
    f16(*buf)[16 * S0] = (f16(*)[16 * S0])smem;
    int bt = wg;
    int n = g * 16 + col;                      // output neuron (0..159, valid <149)
    h8 Bf[3][5];                               // recurrent weights, resident
#pragma unroll
    for (int mat = 0; mat < 3; mat++)
#pragma unroll
      for (int kt = 0; kt < 5; kt++)
        Bf[mat][kt] = pk[OFF_R0 + ((g * 3 + mat) * 5 + kt) * 64 + lane];

    for (int idx = tid; idx < 16 * S0; idx += 640) {
      buf[0][idx] = (c == 0) ? (f16)0.f : H0S[(size_t)bt * 16 * S0 + idx];
      buf[1][idx] = (f16)0.f;
    }
    __syncthreads();

    h4 xu0[3], xu1[3], xu2[3], xu3[3];         // depth-4 prefetch (2-step lead)
#pragma unroll
    for (int mat = 0; mat < 3; mat++) {
      xu0[mat] = *(const h4*)(XU0r + ((size_t)(0 * NBT + bt) * NT0 + mat * 10 + g) * 256 + lane * 4);
      xu1[mat] = *(const h4*)(XU0r + ((size_t)(1 * NBT + bt) * NT0 + mat * 10 + g) * 256 + lane * 4);
      xu2[mat] = *(const h4*)(XU0r + ((size_t)(2 * NBT + bt) * NT0 + mat * 10 + g) * 256 + lane * 4);
      xu3[mat] = *(const h4*)(XU0r + ((size_t)(3 * NBT + bt) * NT0 + mat * 10 + g) * 256 + lane * 4);
    }

    for (int t = 0; t < TC; t += 4) {
      r0_step(buf[0], buf[1], XU0r, NH0w, out, Bf, xu0, t, (t + 4 < TC) ? t + 4 : t,
              bt, g, lane, col, q, n, false);
      RAW_BAR();
      r0_step(buf[1], buf[0], XU0r, NH0w, out, Bf, xu1, t + 1,
              (t + 5 < TC) ? t + 5 : t + 1, bt, g, lane, col, q, n, false);
      RAW_BAR();
      r0_step(buf[0], buf[1], XU0r, NH0w, out, Bf, xu2, t + 2,
              (t + 6 < TC) ? t + 6 : t + 2, bt, g, lane, col, q, n, false);
      RAW_BAR();
      bool lastD = (c == NCH - 1) && (t + 3 == TC - 1);
      r0_step(buf[1], buf[0], XU0r, NH0w, out, Bf, xu3, t + 3,
              (t + 7 < TC) ? t + 7 : t + 3, bt, g, lane, col, q, n, lastD);
      RAW_BAR();
    }
    for (int idx = tid; idx < 16 * S0; idx += 640)
      H0S[(size_t)bt * 16 * S0 + idx] = buf[0][idx];

  } else if (wg < 2 * NBT) {  // ================= r12, chunk cc = c-1 =================
    int cc = c - 1;
    if (cc < 0 || cc >= NCH) return;
    const f16* XU1r = XU1 + (size_t)(cc & 1) * XU1C;
    f16(*buf)[16 * S2] = (f16(*)[16 * S2])smem;
    int bt = wg - NBT;
    int w = g;                                 // wave id 0..9 (8,9 barrier-only)
    int n = w * 16 + col;
    h8 Bf[3][4];
    float bn0 = 0.f, bn1 = 0.f, bn2 = 0.f;
    if (w < 7) {
#pragma unroll
      for (int mat = 0; mat < 3; mat++)
#pragma unroll
        for (int kt = 0; kt < 4; kt++)
          Bf[mat][kt] = pk[OFF_R12A + ((w * 3 + mat) * 4 + kt) * 64 + lane];
    } else if (w == 7) {
#pragma unroll
      for (int mat = 0; mat < 3; mat++)
#pragma unroll
        for (int kt = 0; kt < 4; kt++)
          Bf[mat][kt] = pk[OFF_R12B + (mat * 4 + kt) * 64 + lane];
      bn0 = (col < Nm) ? -2.f * L2E * c1[col] : 0.f;
      bn1 = (col < Nm) ? -2.f * L2E * c2[col] : 0.f;
      bn2 = (col < Nm) ? -L2E * (ts * ca[col] + cb[col]) : 0.f;
    }
    for (int idx = tid; idx < 2 * 16 * S2; idx += 640)
      ((f16*)buf)[idx] = (cc == 0) ? (f16)0.f : H12S[(size_t)bt * 2 * 16 * S2 + idx];
    __syncthreads();

    // ---- wait for x1(cc) (same launch) to finish producing XU1(cc) ----
    if (tid == 0) {
      long it = 0;
      while (__hip_atomic_load(&CNT[cc], __ATOMIC_RELAXED,
                               __HIP_MEMORY_SCOPE_AGENT) < NXWG1 &&
             it < (1L << 28)) {
        __builtin_amdgcn_s_sleep(8);
        ++it;
      }
    }
    __syncthreads();
    __builtin_amdgcn_fence(__ATOMIC_ACQUIRE, "agent");  // invalidate stale XU1 lines

    h4 xuA[3], xuB[3];                         // depth-2 prefetch register sets
    if (w < 7) {
#pragma unroll
      for (int mat = 0; mat < 3; mat++) {
        xuA[mat] = *(const h4*)(XU1r + ((size_t)bt * NT1 + mat * 7 + w) * 256 + lane * 4);
        xuB[mat] = *(const h4*)(XU1r +
                                ((size_t)(NBT + bt) * NT1 + mat * 7 + w) * 256 + lane * 4);
      }
    }

    for (int t = 0; t < TC; t += 2) {
      if (w < 7) {
        int tlA = (t + 2 < TC) ? t + 2 : t;
        r12l1_step(buf[0], buf[1], XU1r, out, Bf, xuA, tlA, bt, w, lane, col, q, n,
                   false);                                  // last never hits even t
      }
      RAW_BAR();
      if (w == 7)
        r12l2_step(buf[1], buf[0], out, Bf, bn0, bn1, bn2, cc * TC + t, bt, col, q,
                   false);
      if (w < 7) {
        int tlB = (t + 3 < TC) ? t + 3 : t + 1;
        bool lastB = (cc == NCH - 1) && (t + 1 == TC - 1);
        r12l1_step(buf[1], buf[0], XU1r, out, Bf, xuB, tlB, bt, w, lane, col, q, n,
                   lastB);
      }
      RAW_BAR();
      if (w == 7)
        r12l2_step(buf[0], buf[1], out, Bf, bn0, bn1, bn2, cc * TC + t + 1, bt, col, q,
                   (cc == NCH - 1) && (t + 1 == TC - 1));
    }
    __syncthreads();
    for (int idx = tid; idx < 2 * 16 * S2; idx += 640)
      H12S[(size_t)bt * 2 * 16 * S2 + idx] = ((f16*)buf)[idx];

  } else if (wg < 2 * NBT + NXWG1) {  // ========= x1 for chunk c-1 (bulk) =========
    int cx = c - 1;
    if (cx < 0 || cx >= NCH) return;
    int w = g;
    const f16* NH0r = NH0 + (size_t)(cx & 1) * NH0C;
    f16* XU1w = XU1 + (size_t)(cx & 1) * XU1C;
    int bx = wg - 2 * NBT;                     // 0..NXWG1-1
    int n = w * 16 + col;                      // wave w -> n-tile w, all 3 mats
    if (w < 7) {
      h8 Bf[3][5];
      float bias[3];
#pragma unroll
      for (int mat = 0; mat < 3; mat++)
#pragma unroll
        for (int kt = 0; kt < 5; kt++)
          Bf[mat][kt] = pk[OFF_X1 + (mat * 35 + w * 5 + kt) * 64 + lane];
      bias[0] = (n < Nc) ? -2.f * L2E * b1_1[n] : 0.f;
      bias[1] = (n < Nc) ? -2.f * L2E * b2_1[n] : 0.f;
      bias[2] = (n < Nc) ? -L2E * (ts * ba_1[n] + bb_1[n]) : 0.f;
      for (int i = 0; i < (TC * NBT) / NXWG1; i++) {   // 16 mt tiles per WG
        int mt = bx * ((TC * NBT) / NXWG1) + i;
        const f16* Ab = NH0r + (size_t)mt * 2560;      // 16x160 halves, zero-padded
        h8 A[5];
#pragma unroll
        for (int kt = 0; kt < 5; kt++)
          A[kt] = *(const h8*)(Ab + col * 160 + kt * 32 + q * 8);
#pragma unroll
        for (int mat = 0; mat < 3; mat++) {
          float b = bias[mat];
          f4 acc = {b, b, b, b};
#pragma unroll
          for (int kt = 0; kt < 5; kt++) acc = MFMA(A[kt], Bf[mat][kt], acc);
          h4 o;
#pragma unroll
          for (int rr = 0; rr < 4; rr++) o[rr] = (f16)acc[rr];
          *(h4*)(XU1w + ((size_t)mt * NT1 + mat * 7 + w) * 256 + lane * 4) = o;
        }
      }
    }
    // all waves (incl. idle 7-9) sync, then one release-add announces this WG done
    __syncthreads();
    if (tid == 0)
      __hip_atomic_fetch_add(&CNT[cx], 1, __ATOMIC_RELEASE,
                             __HIP_MEMORY_SCOPE_AGENT);

  } else {  // ================= x0 for chunk c+1 (no recurrence dep) =================
    int cn = c + 1;
    if (cn >= NCH) return;
    f16* XU0w = XU0 + (size_t)(cn & 1) * XU0C;
    f16* stg = (f16*)smem;                     // 16 x 136
    int bx = wg - 2 * NBT - NXWG1;             // 0..NXWG0-1
    int w = g;                                 // wave -> output tile g=w, all 3 mats
    int n = w * 16 + col;
    h8 Bx[3][4];
    float bias[3];
#pragma unroll
    for (int mat = 0; mat < 3; mat++)
#pragma unroll
      for (int kt = 0; kt < 4; kt++)
        Bx[mat][kt] = pk[OFF_X0 + ((mat * 10 + w) * 4 + kt) * 64 + lane];
    bias[0] = (n < Ni) ? -2.f * L2E * b1_0[n] : 0.f;
    bias[1] = (n < Ni) ? -2.f * L2E * b2_0[n] : 0.f;
    bias[2] = (n < Ni) ? -L2E * (ts * ba_0[n] + bb_0[n]) : 0.f;
    for (int i = 0; i < (TC * NBT) / NXWG0; i++) {   // 8 mt tiles per WG
      int mt = bx * ((TC * NBT) / NXWG0) + i;
      int tl = mt >> 4, bt = mt & 15;
      int tg = cn * TC + tl;
      if (tid < 256) {
        int sr = tid >> 4, sc = (tid & 15) * 8;
        const float* xp = x + ((size_t)(bt * 16 + sr) * Tsz + tg) * IN_DIM + sc;
        h8 hv;
#pragma unroll
        for (int j = 0; j < 8; j++) hv[j] = (f16)xp[j];
        *(h8*)(stg + sr * 136 + sc) = hv;
      }
      __syncthreads();
      h8 A[4];
#pragma unroll
      for (int kt = 0; kt < 4; kt++)
        A[kt] = *(const h8*)(stg + col * 136 + kt * 32 + q * 8);
#pragma unroll
      for (int mat = 0; mat < 3; mat++) {
        float b = bias[mat];
        f4 acc = {b, b, b, b};
#pragma unroll
        for (int kt = 0; kt < 4; kt++) acc = MFMA(A[kt], Bx[mat][kt], acc);
        h4 o;
#pragma unroll
        for (int rr = 0; rr < 4; rr++) o[rr] = (f16)acc[rr];
        *(h4*)(XU0w + ((size_t)mt * NT0 + mat * 10 + w) * 256 + lane * 4) = o;
      }
      __syncthreads();
    }
  }
}

extern "C" void kernel_launch(void* const* d_in, const int* in_sizes, int n_in,
                              void* d_out, int out_size, void* d_ws, size_t ws_size,
                              hipStream_t stream) {
  const float* w1_0 = (const float*)d_in[0];
  const float* w2_0 = (const float*)d_in[1];
  const float* wa_0 = (const float*)d_in[2];
  const float* wb_0 = (const float*)d_in[3];
  const float* b1_0 = (const float*)d_in[4];
  const float* b2_0 = (const float*)d_in[5];
  const float* ba_0 = (const float*)d_in[6];
  const float* bb_0 = (const float*)d_in[7];
  const int* m0 = (const int*)d_in[8];
  const float* w1_1 = (const float*)d_in[9];
  const float* w2_1 = (const float*)d_in[10];
  const float* wa_1 = (const float*)d_in[11];
  const float* wb_1 = (const float*)d_in[12];
  const float* b1_1 = (const float*)d_in[13];
  const float* b2_1 = (const float*)d_in[14];
  const float* ba_1 = (const float*)d_in[15];
  const float* bb_1 = (const float*)d_in[16];
  const int* m1 = (const int*)d_in[17];
  const float* w1_2 = (const float*)d_in[18];
  const float* w2_2 = (const float*)d_in[19];
  const float* wa_2 = (const float*)d_in[20];
  const float* wb_2 = (const float*)d_in[21];
  const float* c1 = (const float*)d_in[22];
  const float* c2 = (const float*)d_in[23];
  const float* ca = (const float*)d_in[24];
  const float* cb = (const float*)d_in[25];
  const int* m2 = (const int*)d_in[26];
  const float* x = (const float*)d_in[27];
  const float* dt = (const float*)d_in[28];
  float* out = (float*)d_out;

  f16* XU0 = (f16*)d_ws;                 // 2 x XU0C
  f16* NH0 = XU0 + 2 * XU0C;             // 2 x NH0C
  f16* XU1 = NH0 + 2 * NH0C;             // 2 x XU1C
  f16* H0S = XU1 + 2 * XU1C;
  f16* H12S = H0S + H0S_HALVES;
  f16* PK = H12S + H12S_HALVES;
  int* CNT = (int*)(PK + (size_t)NFRAG * 8);
  const h8* pk = (const h8*)PK;

  pack_kernel<<<(NFRAG + 255) / 256, 256, 0, stream>>>(
      w1_0, w2_0, wa_0, wb_0, m0, w1_1, w2_1, wa_1, wb_1, m1,
      w1_2, w2_2, wa_2, wb_2, m2, dt, PK, CNT);

  for (int c = -1; c <= NCH; c++)
    R_kernel<<<2 * NBT + NXWG1 + NXWG0, 640, 0, stream>>>(
        pk, b1_0, b2_0, ba_0, bb_0, b1_1, b2_1, ba_1, bb_1,
        c1, c2, ca, cb, dt, x, XU0, NH0, XU1, H0S, H12S, CNT, out, c);
}